// Round 1
// 1339.167 us; speedup vs baseline: 1.0175x; 1.0175x over previous
//
#include <hip/hip_runtime.h>

#define N_DIM          64
#define N_IMAGES       1024
#define ROWS_PER_BLOCK 2048
#define THREADS        256

typedef float v4f __attribute__((ext_vector_type(4)));
typedef int   v4i __attribute__((ext_vector_type(4)));

__device__ __forceinline__ v4f ldx(const float* __restrict__ p) {
    return __builtin_nontemporal_load((const v4f*)p);
}

// Phase A: per-block contiguous chunk of 2048 rows.
//  - id copy (int4 -> float4, nontemporal stores)
//  - segment sums, software-pipelined one group (4 sampled rows) ahead:
//    the 4 x-row loads + the group's guard id are issued UNCONDITIONALLY for
//    group g+1 before group g is consumed. No load is control-dependent on
//    the id compare, so the consume-side s_waitcnt is a partial vmcnt that
//    is already satisfied -> the HBM read stream never drains.
__global__ __launch_bounds__(THREADS) void ImageAverage_phaseA(
    const float* __restrict__ x,
    const int*   __restrict__ ids,
    float*       __restrict__ accum,     // [N_IMAGES * N_DIM] fp32, pre-zeroed
    int*         __restrict__ counts,    // [N_IMAGES] int32, pre-zeroed
    float*       __restrict__ out_id)    // [n_reflns] float copy of ids
{
    const int t = threadIdx.x;
    const long long blockRow0 = (long long)blockIdx.x * ROWS_PER_BLOCK;

    // ---- id copy: fully coalesced, nontemporal ----
    {
        const v4i* idv  = (const v4i*)(ids + blockRow0);
        v4f*       outv = (v4f*)(out_id + blockRow0);
        const int niter = ROWS_PER_BLOCK / 4 / THREADS;   // 2
        #pragma unroll
        for (int k = 0; k < niter; ++k) {
            v4i v = idv[k * THREADS + t];
            v4f f;
            f.x = (float)v.x; f.y = (float)v.y; f.z = (float)v.z; f.w = (float)v.w;
            __builtin_nontemporal_store(f, &outv[k * THREADS + t]);
        }
    }

    // ---- segment sums ----
    // thread -> 4 consecutive dims (float4), rows strided by 16
    const int dimGroup = t & 15;        // 0..15
    const int d0       = dimGroup * 4;  // starting dim
    const int rowOff   = t >> 4;        // 0..15
    const bool isCounter = (dimGroup == 0);

    v4f sum = {0.f, 0.f, 0.f, 0.f};
    int cnt = 0;

    long long row = blockRow0 + rowOff;
    int cur = ids[row];

    // consume one group of 4 sampled rows whose values are already in registers
    auto consume = [&](v4f a, v4f b, v4f c, v4f d, int idLast, long long grow) {
        if (idLast == cur) {
            // fast path: sorted ids + id[last]==cur => all 4 rows belong to cur
            sum += (a + b) + (c + d);
            cnt += 4;
        } else {
            // slow path: boundary inside the group (rare). Values already
            // loaded; only the 3 interior ids need (L2-hot) loads.
            #pragma unroll
            for (int k = 0; k < 4; ++k) {
                const int id = (k < 3) ? ids[grow + 16 * k] : idLast;
                const v4f v = (k == 0) ? a : (k == 1) ? b : (k == 2) ? c : d;
                if (id != cur) {
                    float* ap = accum + (long long)cur * N_DIM + d0;
                    atomicAdd(ap + 0, sum.x);
                    atomicAdd(ap + 1, sum.y);
                    atomicAdd(ap + 2, sum.z);
                    atomicAdd(ap + 3, sum.w);
                    if (isCounter) atomicAdd(&counts[cur], cnt);
                    sum = (v4f){0.f, 0.f, 0.f, 0.f};
                    cnt = 0;
                    cur = id;
                }
                sum += v;
                cnt++;
            }
        }
    };

    const int NGROUPS = ROWS_PER_BLOCK / 16 / 4;   // 32 groups of 4 sampled rows

    // prologue: group 0 loads
    v4f a = ldx(x + row * N_DIM + d0);
    v4f b = ldx(x + (row + 16) * N_DIM + d0);
    v4f c = ldx(x + (row + 32) * N_DIM + d0);
    v4f d = ldx(x + (row + 48) * N_DIM + d0);
    int idLast = ids[row + 48];

    for (int g = 0; g < NGROUPS - 1; ++g) {
        const long long rown = row + 64;
        // prefetch group g+1 (always in-bounds within the block: no guard)
        const v4f an = ldx(x + rown * N_DIM + d0);
        const v4f bn = ldx(x + (rown + 16) * N_DIM + d0);
        const v4f cn = ldx(x + (rown + 32) * N_DIM + d0);
        const v4f dn = ldx(x + (rown + 48) * N_DIM + d0);
        const int idLn = ids[rown + 48];

        consume(a, b, c, d, idLast, row);

        a = an; b = bn; c = cn; d = dn; idLast = idLn; row = rown;
    }

    // epilogue: last group
    consume(a, b, c, d, idLast, row);

    // final flush
    {
        float* ap = accum + (long long)cur * N_DIM + d0;
        atomicAdd(ap + 0, sum.x);
        atomicAdd(ap + 1, sum.y);
        atomicAdd(ap + 2, sum.z);
        atomicAdd(ap + 3, sum.w);
        if (isCounter) atomicAdd(&counts[cur], cnt);
    }
}

// Phase B: averaged = accum / max(count,1); counts -> float tail
__global__ __launch_bounds__(THREADS) void ImageAverage_phaseB(
    const float* __restrict__ accum,
    const int*   __restrict__ counts,
    float*       __restrict__ out_avg,     // [N_IMAGES * N_DIM]
    float*       __restrict__ out_counts)  // [N_IMAGES]
{
    const int i = blockIdx.x * blockDim.x + threadIdx.x;
    if (i < N_IMAGES * N_DIM) {
        const int img = i >> 6;   // / N_DIM
        const int c = counts[img];
        const float denom = (float)(c > 0 ? c : 1);
        out_avg[i] = accum[i] / denom;
    }
    if (i < N_IMAGES) {
        out_counts[i] = (float)counts[i];
    }
}

extern "C" void kernel_launch(void* const* d_in, const int* in_sizes, int n_in,
                              void* d_out, int out_size, void* d_ws, size_t ws_size,
                              hipStream_t stream) {
    const float* x   = (const float*)d_in[0];
    const int*   ids = (const int*)d_in[1];
    const int n_reflns = in_sizes[1];          // 4194304

    // output layout (all float32): [avg 1024*64][id copy n_reflns][counts 1024]
    float* out_avg    = (float*)d_out;
    float* out_id     = out_avg + (size_t)N_IMAGES * N_DIM;
    float* out_counts = out_id + (size_t)n_reflns;

    // workspace: [accum 1024*64 fp32][counts 1024 int32]
    float* accum  = (float*)d_ws;
    int*   counts = (int*)((char*)d_ws + (size_t)N_IMAGES * N_DIM * sizeof(float));

    hipMemsetAsync(d_ws, 0,
                   (size_t)N_IMAGES * N_DIM * sizeof(float) + (size_t)N_IMAGES * sizeof(int),
                   stream);

    const int gridA = n_reflns / ROWS_PER_BLOCK;   // 2048 -> 8 blocks/CU, 32 waves/CU
    ImageAverage_phaseA<<<gridA, THREADS, 0, stream>>>(x, ids, accum, counts, out_id);

    const int nB = N_IMAGES * N_DIM;               // 65536
    ImageAverage_phaseB<<<(nB + THREADS - 1) / THREADS, THREADS, 0, stream>>>(
        accum, counts, out_avg, out_counts);
}